// Round 4
// baseline (173.641 us; speedup 1.0000x reference)
//
#include <hip/hip_runtime.h>
#include <math.h>

#define N_ROWS 16384
#define M_COLS 8192
#define TPB 256
#define IT 4                        // i-rows per thread (ILP chains)
#define JT 128                      // j-tile per block (LDS staged)
#define NJ (M_COLS / JT)            // 64 j-chunks
#define NIB (N_ROWS / (TPB * IT))   // 16 i-blocks
#define PAIR_BLOCKS (NIB * NJ)      // 1024
#define EDGE_BLOCKS 2048
#define EU 4                        // edges per thread (batched gathers)
#define GRID_BLOCKS (PAIR_BLOCKS + EDGE_BLOCKS)   // 3072

typedef float v2f __attribute__((ext_vector_type(2)));
typedef _Float16 h8 __attribute__((ext_vector_type(8)));

#define C2 2.0813689810056077f      // log2(e)^2 — folded into the quadratic form

// ---------- kernel 1: fused row softmax for BOTH z and w ----------
// stores: simplex row f32 (pair), simplex row f16 (edge gathers),
//         C2*||row||^2, exp(gamma)
__global__ __launch_bounds__(TPB) void rownorm_kernel(
    const float* __restrict__ lz, const float* __restrict__ gr,
    const float* __restrict__ lw, const float* __restrict__ gc,
    float* __restrict__ z, float* __restrict__ zz, float* __restrict__ eg,
    _Float16* __restrict__ zh,
    float* __restrict__ w, float* __restrict__ ww, float* __restrict__ ec,
    _Float16* __restrict__ wh)
{
    int gi = blockIdx.x * TPB + threadIdx.x;
    const float *src, *g;
    float *dv, *dq, *de;
    _Float16* dh;
    int i;
    if (gi < N_ROWS) { src = lz; g = gr; dv = z; dq = zz; de = eg; dh = zh; i = gi; }
    else             { src = lw; g = gc; dv = w; dq = ww; de = ec; dh = wh; i = gi - N_ROWS; }

    const float4* sp = (const float4*)(src + (size_t)i * 8);
    float4 a = sp[0], b = sp[1];
    float v[8] = {a.x, a.y, a.z, a.w, b.x, b.y, b.z, b.w};
    float m = v[0];
    #pragma unroll
    for (int d = 1; d < 8; d++) m = fmaxf(m, v[d]);
    float s = 0.f;
    #pragma unroll
    for (int d = 0; d < 8; d++) { v[d] = __expf(v[d] - m); s += v[d]; }
    float inv = 1.f / s;
    float sq = 0.f;
    h8 hv;
    #pragma unroll
    for (int d = 0; d < 8; d++) {
        v[d] *= inv;
        sq = fmaf(v[d], v[d], sq);
        hv[d] = (_Float16)v[d];
    }
    float4 o0 = {v[0], v[1], v[2], v[3]};
    float4 o1 = {v[4], v[5], v[6], v[7]};
    float4* dp = (float4*)(dv + (size_t)i * 8);
    dp[0] = o0; dp[1] = o1;
    *(h8*)(dh + (size_t)i * 8) = hv;
    dq[i] = C2 * sq;                 // pre-scaled for the exp2 trick
    de[i] = __expf(g[i]);
}

// ---------- kernel 2: fused pair + edge (role by bid%3) ----------
// rem==0 (1024 blocks): pair sum  S1 = sum_ij eg_i*exp(-dist_ij)*ec_j  (VALU)
// rem!=0 (2048 blocks): edge sum  S2 = sum_e wt_e*(gr[r]+gc[c]-dist_e) (gather)
__global__ __launch_bounds__(TPB) void fused_kernel(
    const float* __restrict__ z, const float* __restrict__ zz,
    const float* __restrict__ eg,
    const float* __restrict__ w, const float* __restrict__ ww,
    const float* __restrict__ ec,
    const _Float16* __restrict__ zh, const _Float16* __restrict__ wh,
    const float* __restrict__ gr, const float* __restrict__ gc,
    const float* __restrict__ wt,
    const int* __restrict__ ridx, const int* __restrict__ cidx, int E,
    double* __restrict__ pair_part, double* __restrict__ edge_part)
{
    __shared__ float  sw[JT * 8];    // w tile [JT][8]
    __shared__ float  swq[JT];       // C2*||w_j||^2
    __shared__ float  sec[JT];       // exp(gamma_cols[j])
    __shared__ double sred[TPB];

    const int t     = threadIdx.x;
    const int bid   = blockIdx.x;
    const int third = bid / 3;
    const int rem   = bid - third * 3;

    if (rem == 0) {
        // ================= PAIR ROLE =================
        const int rid = third;
        const int ib = rid / NJ;
        const int jb = rid - ib * NJ;
        const int j0 = jb * JT;

        ((float4*)sw)[t] = ((const float4*)(w + (size_t)j0 * 8))[t];
        if (t < JT) { swq[t] = ww[j0 + t]; sec[t] = ec[j0 + t]; }

        // z rows pre-scaled by -2*C2: sq' = C2*(zz+ww-2dot), pure pk-FMA chain
        v2f  zi[IT][4];
        float zzi[IT], acc[IT];
        const int ibase = ib * (TPB * IT);
        #pragma unroll
        for (int k = 0; k < IT; k++) {
            int i = ibase + k * TPB + t;
            const float4* zp = (const float4*)(z + (size_t)i * 8);
            float4 a = zp[0], b = zp[1];
            zi[k][0] = (v2f){-2.f * C2 * a.x, -2.f * C2 * a.y};
            zi[k][1] = (v2f){-2.f * C2 * a.z, -2.f * C2 * a.w};
            zi[k][2] = (v2f){-2.f * C2 * b.x, -2.f * C2 * b.y};
            zi[k][3] = (v2f){-2.f * C2 * b.z, -2.f * C2 * b.w};
            zzi[k] = zz[i];
            acc[k] = 0.f;
        }
        __syncthreads();

        const float4* s4 = (const float4*)sw;
        // register double-buffer: prefetch j+1's w row while computing j,
        // hiding the ~120-cyc LDS latency under the k-bodies
        float4 wa = s4[0], wb = s4[1];
        float wq = swq[0], e = sec[0];
        for (int j = 0; j < JT; j++) {
            const int jn = (j + 1) & (JT - 1);
            float4 wan = s4[jn * 2], wbn = s4[jn * 2 + 1];
            float wqn = swq[jn], en = sec[jn];

            v2f w01 = {wa.x, wa.y}, w23 = {wa.z, wa.w};
            v2f w45 = {wb.x, wb.y}, w67 = {wb.z, wb.w};
            #pragma unroll
            for (int k = 0; k < IT; k++) {
                v2f p = {zzi[k], wq};
                p = __builtin_elementwise_fma(zi[k][0], w01, p);
                p = __builtin_elementwise_fma(zi[k][1], w23, p);
                v2f q = zi[k][2] * w45;
                q = __builtin_elementwise_fma(zi[k][3], w67, q);
                p += q;
                float sq = fmaxf(p.x + p.y, 0.f);
                float d, pr;
                asm("v_sqrt_f32 %0, %1" : "=v"(d) : "v"(sq));
                asm("v_exp_f32 %0, -%1" : "=v"(pr) : "v"(d));  // 2^(-d') = e^(-dist)
                acc[k] = fmaf(e, pr, acc[k]);
            }
            wa = wan; wb = wbn; wq = wqn; e = en;
        }

        double tp = 0.0;
        #pragma unroll
        for (int k = 0; k < IT; k++) {
            int i = ibase + k * TPB + t;
            tp += (double)eg[i] * (double)acc[k];
        }

        sred[t] = tp;
        __syncthreads();
        for (int s = TPB / 2; s > 0; s >>= 1) {
            if (t < s) sred[t] += sred[t + s];
            __syncthreads();
        }
        if (t == 0) pair_part[rid] = sred[0];
    } else {
        // ================= EDGE ROLE =================
        const int erank = 2 * third + (rem - 1);      // 0..2047
        const int tid = erank * TPB + t;
        const int e0 = tid * EU;                      // E % EU == 0
        double local = 0.0;
        if (e0 < E) {
            // coalesced meta loads (4 edges per thread)
            int4   rr  = *(const int4*)(ridx + e0);
            int4   cc  = *(const int4*)(cidx + e0);
            float4 wt4 = *(const float4*)(wt + e0);
            int   r[EU]  = {rr.x, rr.y, rr.z, rr.w};
            int   c[EU]  = {cc.x, cc.y, cc.z, cc.w};
            float wv[EU] = {wt4.x, wt4.y, wt4.z, wt4.w};
            // issue ALL gathers before any compute (max MLP):
            // f16 rows -> one dwordx4 line-request per row
            h8 zr[EU], wr[EU];
            float grv[EU], gcv[EU];
            #pragma unroll
            for (int u = 0; u < EU; u++) {
                zr[u]  = *(const h8*)(zh + (size_t)r[u] * 8);
                wr[u]  = *(const h8*)(wh + (size_t)c[u] * 8);
                grv[u] = gr[r[u]];
                gcv[u] = gc[c[u]];
            }
            #pragma unroll
            for (int u = 0; u < EU; u++) {
                h8 dv = zr[u] - wr[u];                // v_pk_add_f16 (neg)
                float s = 0.f;
                #pragma unroll
                for (int qd = 0; qd < 8; qd++) {
                    float f = (float)dv[qd];
                    s = fmaf(f, f, s);
                }
                float dist;
                asm("v_sqrt_f32 %0, %1" : "=v"(dist) : "v"(s));
                local += (double)(wv[u] * (grv[u] + gcv[u] - dist));
            }
        }
        sred[t] = local;
        __syncthreads();
        for (int s2 = TPB / 2; s2 > 0; s2 >>= 1) {
            if (t < s2) sred[t] += sred[t + s2];
            __syncthreads();
        }
        if (t == 0) edge_part[erank] = sred[0];
    }
}

// ---------- kernel 3: final deterministic combine ----------
__global__ __launch_bounds__(TPB) void final_kernel(
    const double* __restrict__ pp, int np,
    const double* __restrict__ ep, int ne,
    float* __restrict__ out)
{
    __shared__ double sred[TPB];
    const int t = threadIdx.x;
    double s1 = 0.0, s2 = 0.0;
    for (int i = t; i < np; i += TPB) s1 += pp[i];
    for (int i = t; i < ne; i += TPB) s2 += ep[i];
    sred[t] = s1;
    __syncthreads();
    for (int s = TPB / 2; s > 0; s >>= 1) {
        if (t < s) sred[t] += sred[t + s];
        __syncthreads();
    }
    double pair_sum = sred[0];
    __syncthreads();
    sred[t] = s2;
    __syncthreads();
    for (int s = TPB / 2; s > 0; s >>= 1) {
        if (t < s) sred[t] += sred[t + s];
        __syncthreads();
    }
    if (t == 0) {
        double edge_sum = sred[0];
        double cf = exp(-1.0e-6);   // exp(-EPS) factored out of the pair term
        out[0] = (float)(cf * pair_sum - edge_sum);
    }
}

extern "C" void kernel_launch(void* const* d_in, const int* in_sizes, int n_in,
                              void* d_out, int out_size, void* d_ws, size_t ws_size,
                              hipStream_t stream)
{
    const float* gamma_rows = (const float*)d_in[0];   // [N]
    const float* gamma_cols = (const float*)d_in[1];   // [M]
    const float* latent_z   = (const float*)d_in[2];   // [N,8]
    const float* latent_w   = (const float*)d_in[3];   // [M,8]
    const float* weights    = (const float*)d_in[4];   // [E]
    const int*   rows_idx   = (const int*)d_in[5];     // [E]
    const int*   col_idx    = (const int*)d_in[6];     // [E]
    float* out = (float*)d_out;
    const int E = in_sizes[4];

    // workspace layout (segments 256B-aligned); total ~1.4 MB
    char* base = (char*)d_ws;
    size_t off = 0;
    float* z  = (float*)(base + off); off += (size_t)N_ROWS * 8 * 4;   // 512 KB
    float* zz = (float*)(base + off); off += (size_t)N_ROWS * 4;       //  64 KB
    float* eg = (float*)(base + off); off += (size_t)N_ROWS * 4;       //  64 KB
    float* w  = (float*)(base + off); off += (size_t)M_COLS * 8 * 4;   // 256 KB
    float* ww = (float*)(base + off); off += (size_t)M_COLS * 4;       //  32 KB
    float* ec = (float*)(base + off); off += (size_t)M_COLS * 4;       //  32 KB
    _Float16* zh = (_Float16*)(base + off); off += (size_t)N_ROWS * 8 * 2; // 256 KB
    _Float16* wh = (_Float16*)(base + off); off += (size_t)M_COLS * 8 * 2; // 128 KB
    double* pair_part = (double*)(base + off); off += (size_t)PAIR_BLOCKS * 8;
    double* edge_part = (double*)(base + off); off += (size_t)EDGE_BLOCKS * 8;
    (void)ws_size;

    rownorm_kernel<<<(N_ROWS + M_COLS) / TPB, TPB, 0, stream>>>(
        latent_z, gamma_rows, latent_w, gamma_cols,
        z, zz, eg, zh, w, ww, ec, wh);
    fused_kernel<<<GRID_BLOCKS, TPB, 0, stream>>>(
        z, zz, eg, w, ww, ec, zh, wh, gamma_rows, gamma_cols,
        weights, rows_idx, col_idx, E, pair_part, edge_part);
    final_kernel<<<1, TPB, 0, stream>>>(pair_part, PAIR_BLOCKS,
                                        edge_part, EDGE_BLOCKS, out);
}